// Round 1
// 3271.703 us; speedup vs baseline: 1.4079x; 1.4079x over previous
//
#include <hip/hip_runtime.h>

// GRU: T=1024 B=64 D=256 H=512 O=256.
// Round 3: remove the flag round-trip from the per-step critical path.
// hs is pre-filled with bf16 NaN sentinel (0x7FC0) each launch; h values are
// finite (|h|<=1) so f2b can never produce the sentinel. Consumers poll the
// DATA itself with read-through (sc0 sc1) 16B loads and consume the polled
// registers directly -- data arrival IS the ready signal. Producer-side
// vmcnt(0) drain and flag store are deleted; h is repacked via a 1KB LDS
// buffer so one wave issues 64 wide 16B sc0sc1 stores (was 512x 2B).
// MFMA accumulate chains split in two; tanh via branch-free __expf.

#define T_ 1024
#define B_ 64
#define D_ 256
#define H_ 512
#define G_ 1536
#define O_ 256

#define SENT 0x7FC0u   // bf16 NaN: unreachable from f2b(finite)

typedef __attribute__((ext_vector_type(8))) short short8;
typedef __attribute__((ext_vector_type(4))) short short4v;
typedef __attribute__((ext_vector_type(4))) float float4v;
typedef __attribute__((ext_vector_type(4))) unsigned int uint4v;

static __device__ __forceinline__ unsigned short f2b(float f) {
  unsigned u = __builtin_bit_cast(unsigned, f);
  u += 0x7fffu + ((u >> 16) & 1u);          // RNE (finite inputs)
  return (unsigned short)(u >> 16);
}

// ---------------------------------------------------------------- prep ------
__global__ __launch_bounds__(256) void prep_kernel(
    const float* __restrict__ x, const float* __restrict__ Wi,
    const float* __restrict__ Wh, const float* __restrict__ Wo,
    unsigned short* __restrict__ xb, unsigned short* __restrict__ WhT,
    unsigned short* __restrict__ WiT, unsigned short* __restrict__ WoT,
    unsigned short* __restrict__ hs)
{
  const size_t NX4 = (size_t)T_ * B_ * D_ / 4;   // float4 -> 4 bf16
  const size_t NWH = (size_t)G_ * H_;
  const size_t NWI = (size_t)G_ * D_;
  const size_t NWO = (size_t)O_ * H_;
  const size_t NH8 = (size_t)T_ * B_ * H_ / 8;   // uint4 sentinel chunks
  const size_t NTOT = NX4 + NWH + NWI + NWO + NH8;
  size_t i = (size_t)blockIdx.x * blockDim.x + threadIdx.x;
  const size_t stride = (size_t)gridDim.x * blockDim.x;
  for (; i < NTOT; i += stride) {
    if (i < NX4) {
      float4v f = ((const float4v*)x)[i];
      short4v o;
      o[0] = (short)f2b(f[0]); o[1] = (short)f2b(f[1]);
      o[2] = (short)f2b(f[2]); o[3] = (short)f2b(f[3]);
      ((short4v*)xb)[i] = o;
      continue;
    }
    size_t j = i - NX4;
    if (j < NWH) { size_t g = j >> 9, k = j & 511; WhT[j] = f2b(Wh[k * G_ + g]); continue; }
    j -= NWH;
    if (j < NWI) { size_t g = j >> 8, k = j & 255; WiT[j] = f2b(Wi[k * G_ + g]); continue; }
    j -= NWI;
    if (j < NWO) { size_t o = j >> 9, k = j & 511; WoT[j] = f2b(Wo[k * O_ + o]); continue; }
    j -= NWO;
    uint4v sv = {0x7FC07FC0u, 0x7FC07FC0u, 0x7FC07FC0u, 0x7FC07FC0u};
    ((uint4v*)hs)[j] = sv;
  }
}

// ---------------------------------------------------------------- scan ------
// 64 WGs x 384 thr (6 waves). group = wg&3 (16 rows), slice = wg>>2 (32 h-cols).
// wave = s*3 + gk; wave's gate-cols = gk*512 + slice*32 + s*16.
__global__ __launch_bounds__(384, 2) void scan_kernel(
    const unsigned short* __restrict__ xb,
    const unsigned short* __restrict__ WhT,
    const unsigned short* __restrict__ WiT,
    unsigned short* __restrict__ hs,
    const float* __restrict__ bi,
    const float* __restrict__ bhn,
    const float* __restrict__ h0)
{
  const int wg = blockIdx.x;
  const int group = wg & 3;
  const int slice = wg >> 2;
  const int tid = threadIdx.x;
  const int wave = tid >> 6;
  const int lane = tid & 63;
  const int m = lane & 15;
  const int quad = lane >> 4;
  const int gk = wave % 3;
  const int s = wave / 3;
  const int row0 = group * 16;
  const int jbase = slice * 32 + s * 16;
  const int gcol = gk * 512 + jbase + m;

  __shared__ unsigned short hT[16 * 512];     // h tile, XOR-swizzled 16B blocks
  struct HX { float h, x; };
  __shared__ HX lds_hx[6][256];               // pre-activation exchange
  __shared__ unsigned short h_out[16 * 32];   // this WG's h slice (repack)

  // persistent B fragments (weights live in registers for the whole scan)
  short8 Bh[16], Bx[8];
  {
    const unsigned short* p = WhT + (size_t)gcol * H_ + quad * 8;
#pragma unroll
    for (int k = 0; k < 16; ++k) Bh[k] = *(const short8*)(p + k * 32);
    const unsigned short* q = WiT + (size_t)gcol * D_ + quad * 8;
#pragma unroll
    for (int k = 0; k < 8; ++k) Bx[k] = *(const short8*)(q + k * 32);
  }

  const int jcol = jbase + m;
  const float bi_r = bi[jcol];
  const float bi_z = bi[512 + jcol];
  const float bi_n = bi[1024 + jcol];
  const float bhn_c = bhn[jcol];
  float hold[4];
#pragma unroll
  for (int i = 0; i < 4; ++i)
    hold[i] = h0[(size_t)(row0 + quad * 4 + i) * H_ + jcol];

  // preamble: h0 -> hT (bf16, swizzled)
  for (int i = tid; i < 16 * 512; i += 384) {
    int r = i >> 9, c = i & 511;
    int c2 = (((c >> 3) ^ (r & 7)) << 3) | (c & 7);
    hT[r * 512 + c2] = f2b(h0[(size_t)(row0 + r) * H_ + c]);
  }
  // accx for t=0
  float4v accx = {0.f, 0.f, 0.f, 0.f};
  {
    const unsigned short* xp = xb + ((size_t)0 * B_ + row0 + m) * D_ + quad * 8;
#pragma unroll
    for (int k = 0; k < 8; ++k)
      accx = __builtin_amdgcn_mfma_f32_16x16x32_bf16(*(const short8*)(xp + k * 32), Bx[k], accx, 0, 0, 0);
  }
  __syncthreads();

  for (int t = 0; t < T_; ++t) {
    // h-part MFMAs from LDS tile (two accumulators -> half dep-chain depth)
    float4v acch0 = {0.f, 0.f, 0.f, 0.f}, acch1 = {0.f, 0.f, 0.f, 0.f};
#pragma unroll
    for (int k = 0; k < 16; k += 2) {
      const int blk0 = (k * 4 + quad) ^ (m & 7);
      short8 a0 = *(const short8*)&hT[m * 512 + blk0 * 8];
      acch0 = __builtin_amdgcn_mfma_f32_16x16x32_bf16(a0, Bh[k], acch0, 0, 0, 0);
      const int blk1 = ((k + 1) * 4 + quad) ^ (m & 7);
      short8 a1 = *(const short8*)&hT[m * 512 + blk1 * 8];
      acch1 = __builtin_amdgcn_mfma_f32_16x16x32_bf16(a1, Bh[k + 1], acch1, 0, 0, 0);
    }
    // exchange pre-activations (h-part + x-part packed as one b64 each)
#pragma unroll
    for (int i = 0; i < 4; ++i) {
      const int idx = (quad * 4 + i) * 16 + m;
      HX v; v.h = acch0[i] + acch1[i]; v.x = accx[i];
      lds_hx[wave][idx] = v;
    }
    __syncthreads();
    if (gk == 0) {
      const int wb = s * 3;
#pragma unroll
      for (int i = 0; i < 4; ++i) {
        const int r = quad * 4 + i;
        const int idx = r * 16 + m;
        const HX vr = lds_hx[wb + 0][idx];
        const HX vz = lds_hx[wb + 1][idx];
        const HX vn = lds_hx[wb + 2][idx];
        const float pr = vr.h + vr.x + bi_r;
        const float pz = vz.h + vz.x + bi_z;
        const float rg = 1.f / (1.f + __expf(-pr));
        const float zg = 1.f / (1.f + __expf(-pz));
        const float an = vn.x + bi_n + rg * (vn.h + bhn_c);
        const float e2 = __expf(2.f * an);          // branch-free tanh
        const float ng = 1.f - 2.f / (e2 + 1.f);
        const float hn = (1.f - zg) * ng + zg * hold[i];
        hold[i] = hn;
        h_out[r * 32 + s * 16 + m] = f2b(hn);
      }
    }
    // issue x loads for t+1 early (overlap store visibility + poll)
    short8 xa[8];
    if (t < T_ - 1) {
      const unsigned short* xp = xb + ((size_t)(t + 1) * B_ + row0 + m) * D_ + quad * 8;
#pragma unroll
      for (int k = 0; k < 8; ++k) xa[k] = *(const short8*)(xp + k * 32);
    }
    __syncthreads();
    // one wave stores this WG's 1KB h slice as 64x16B write-through stores.
    // No drain, no flag: the data publishes itself.
    if (wave == 1) {
      const int r = lane >> 2, c8 = (lane & 3) * 8;
      short8 hv = *(const short8*)&h_out[r * 32 + c8];
      unsigned short* dst = hs + ((size_t)t * B_ + row0 + r) * H_ + slice * 32 + c8;
      asm volatile("global_store_dwordx4 %0, %1, off sc0 sc1"
                   :: "v"(dst), "v"(hv) : "memory");
    }
    if (t < T_ - 1) {
      // poll hs[t] tile (16 rows x 512 = 1024 x 16B chunks) with read-through
      // loads; a chunk is ready when none of its 8 bf16 equal the sentinel.
      const unsigned short* src = hs + ((size_t)t * B_ + row0) * H_;
      const int c0 = tid, c1 = tid + 384;
      const int c2r = tid + 768;
      const int c2 = (c2r < 1024) ? c2r : c0;     // dup for tail threads
      const short8* p0 = (const short8*)(src + (size_t)c0 * 8);
      const short8* p1 = (const short8*)(src + (size_t)c1 * 8);
      const short8* p2 = (const short8*)(src + (size_t)c2 * 8);
      short8 v0, v1, v2;
      bool bad;
      do {
        // loads + waitcnt in ONE asm block: consumers of v0..v2 can never be
        // scheduled before the vmcnt(0).
        asm volatile(
            "global_load_dwordx4 %0, %3, off sc0 sc1\n\t"
            "global_load_dwordx4 %1, %4, off sc0 sc1\n\t"
            "global_load_dwordx4 %2, %5, off sc0 sc1\n\t"
            "s_waitcnt vmcnt(0)"
            : "=&v"(v0), "=&v"(v1), "=&v"(v2)
            : "v"(p0), "v"(p1), "v"(p2));
        bad = false;
#pragma unroll
        for (int e = 0; e < 8; ++e) {
          bad |= ((unsigned short)v0[e] == (unsigned short)SENT);
          bad |= ((unsigned short)v1[e] == (unsigned short)SENT);
          bad |= ((unsigned short)v2[e] == (unsigned short)SENT);
        }
      } while (bad);
      // write hT swizzled
      { const int r = c0 >> 6, b2 = (c0 & 63) ^ (r & 7); *(short8*)&hT[r * 512 + b2 * 8] = v0; }
      { const int r = c1 >> 6, b2 = (c1 & 63) ^ (r & 7); *(short8*)&hT[r * 512 + b2 * 8] = v1; }
      if (c2r < 1024) { const int r = c2r >> 6, b2 = (c2r & 63) ^ (r & 7); *(short8*)&hT[r * 512 + b2 * 8] = v2; }
      // x MFMAs for t+1 (two accumulators)
      float4v ax0 = {0.f, 0.f, 0.f, 0.f}, ax1 = {0.f, 0.f, 0.f, 0.f};
#pragma unroll
      for (int k = 0; k < 8; k += 2) {
        ax0 = __builtin_amdgcn_mfma_f32_16x16x32_bf16(xa[k], Bx[k], ax0, 0, 0, 0);
        ax1 = __builtin_amdgcn_mfma_f32_16x16x32_bf16(xa[k + 1], Bx[k + 1], ax1, 0, 0, 0);
      }
#pragma unroll
      for (int i = 0; i < 4; ++i) accx[i] = ax0[i] + ax1[i];
      __syncthreads();
    }
  }
}

// ---------------------------------------------------------------- ogemm -----
__global__ __launch_bounds__(256) void ogemm_kernel(
    const unsigned short* __restrict__ hs, const unsigned short* __restrict__ WoT,
    const float* __restrict__ bo, float* __restrict__ out)
{
  const int wv = threadIdx.x >> 6, lane = threadIdx.x & 63;
  const int m = lane & 15, quad = lane >> 4;
  const int rowbase = blockIdx.x * 64 + wv * 16;
  const unsigned short* ap = hs + (size_t)(rowbase + m) * H_ + quad * 8;
  float4v acc[16];
#pragma unroll
  for (int n = 0; n < 16; ++n) { float4v z = {0.f,0.f,0.f,0.f}; acc[n] = z; }
#pragma unroll
  for (int k = 0; k < 16; ++k) {
    short8 a = *(const short8*)(ap + k * 32);
#pragma unroll
    for (int n = 0; n < 16; ++n) {
      short8 b = *(const short8*)(WoT + (size_t)(n * 16 + m) * H_ + k * 32 + quad * 8);
      acc[n] = __builtin_amdgcn_mfma_f32_16x16x32_bf16(a, b, acc[n], 0, 0, 0);
    }
  }
#pragma unroll
  for (int n = 0; n < 16; ++n) {
    const int col = n * 16 + m;
    const float bias = bo[col];
#pragma unroll
    for (int i = 0; i < 4; ++i) {
      const int r = rowbase + quad * 4 + i;
      out[(size_t)r * O_ + col] = acc[n][i] + bias;
    }
  }
}

// ---------------------------------------------------------------- launch ----
extern "C" void kernel_launch(void* const* d_in, const int* in_sizes, int n_in,
                              void* d_out, int out_size, void* d_ws, size_t ws_size,
                              hipStream_t stream)
{
  const float* x   = (const float*)d_in[0];
  const float* Wi  = (const float*)d_in[1];
  const float* bi  = (const float*)d_in[2];
  const float* Wh  = (const float*)d_in[3];
  const float* bhn = (const float*)d_in[4];
  const float* Wo  = (const float*)d_in[5];
  const float* bo  = (const float*)d_in[6];
  const float* h0  = (const float*)d_in[7];
  float* out = (float*)d_out;

  char* ws = (char*)d_ws;
  unsigned short* xb  = (unsigned short*)ws;  ws += (size_t)T_ * B_ * D_ * 2;  // 33.5 MB
  unsigned short* WhT = (unsigned short*)ws;  ws += (size_t)G_ * H_ * 2;       // 1.5 MB
  unsigned short* WiT = (unsigned short*)ws;  ws += (size_t)G_ * D_ * 2;       // 0.75 MB
  unsigned short* WoT = (unsigned short*)ws;  ws += (size_t)O_ * H_ * 2;       // 0.25 MB
  unsigned short* hs  = (unsigned short*)ws;                                    // 67 MB

  prep_kernel<<<4096, 256, 0, stream>>>(x, Wi, Wh, Wo, xb, WhT, WiT, WoT, hs);
  scan_kernel<<<64, 384, 0, stream>>>(xb, WhT, WiT, hs, bi, bhn, h0);
  ogemm_kernel<<<1024, 256, 0, stream>>>(hs, WoT, bo, out);
}

// Round 2
// 3178.192 us; speedup vs baseline: 1.4493x; 1.0294x over previous
//
#include <hip/hip_runtime.h>

// GRU: T=1024 B=64 D=256 H=512 O=256.
// Round 4: XCD-local exchange. Launch 128 WGs; (wg&7)>=4 exit immediately so
// the 64 active WGs have group = wg&7 (<4), slice = wg>>3 -- under round-robin
// XCD dispatch all 16 WGs of a group share one XCD (one shared L2). A one-time
// consensus exchanges HW_REG_XCC_ID through device-scope slots; if a group is
// XCD-homogeneous it switches the h exchange from sc0sc1 (MALL round trip,
// ~2x ~0.5us/step) to sc0-only (write-back into the shared L2, ~200cyc RT):
// stores allocate/update in the one L2 that all group members read with
// L1-bypass loads. hs row-ranges are group-disjoint => single-L2-owner, no
// cross-L2 aliasing. Heterogeneous groups fall back to the proven sc0sc1
// protocol (correct under ANY dispatch mapping). Sentinel self-validation,
// wave decomposition, MFMA structure unchanged from round 3.

#define T_ 1024
#define B_ 64
#define D_ 256
#define H_ 512
#define G_ 1536
#define O_ 256

#define SENT 0x7FC0u   // bf16 NaN: unreachable from f2b(finite)

typedef __attribute__((ext_vector_type(8))) short short8;
typedef __attribute__((ext_vector_type(4))) short short4v;
typedef __attribute__((ext_vector_type(4))) float float4v;
typedef __attribute__((ext_vector_type(4))) unsigned int uint4v;

static __device__ __forceinline__ unsigned short f2b(float f) {
  unsigned u = __builtin_bit_cast(unsigned, f);
  u += 0x7fffu + ((u >> 16) & 1u);          // RNE (finite inputs)
  return (unsigned short)(u >> 16);
}

// ---------------------------------------------------------------- prep ------
__global__ __launch_bounds__(256) void prep_kernel(
    const float* __restrict__ x, const float* __restrict__ Wi,
    const float* __restrict__ Wh, const float* __restrict__ Wo,
    unsigned short* __restrict__ xb, unsigned short* __restrict__ WhT,
    unsigned short* __restrict__ WiT, unsigned short* __restrict__ WoT,
    unsigned short* __restrict__ hs, unsigned* __restrict__ xccbuf)
{
  const size_t NX4 = (size_t)T_ * B_ * D_ / 4;   // float4 -> 4 bf16
  const size_t NWH = (size_t)G_ * H_;
  const size_t NWI = (size_t)G_ * D_;
  const size_t NWO = (size_t)O_ * H_;
  const size_t NH8 = (size_t)T_ * B_ * H_ / 8;   // uint4 sentinel chunks
  const size_t NXC = 128;
  const size_t NTOT = NX4 + NWH + NWI + NWO + NH8 + NXC;
  size_t i = (size_t)blockIdx.x * blockDim.x + threadIdx.x;
  const size_t stride = (size_t)gridDim.x * blockDim.x;
  for (; i < NTOT; i += stride) {
    if (i < NX4) {
      float4v f = ((const float4v*)x)[i];
      short4v o;
      o[0] = (short)f2b(f[0]); o[1] = (short)f2b(f[1]);
      o[2] = (short)f2b(f[2]); o[3] = (short)f2b(f[3]);
      ((short4v*)xb)[i] = o;
      continue;
    }
    size_t j = i - NX4;
    if (j < NWH) { size_t g = j >> 9, k = j & 511; WhT[j] = f2b(Wh[k * G_ + g]); continue; }
    j -= NWH;
    if (j < NWI) { size_t g = j >> 8, k = j & 255; WiT[j] = f2b(Wi[k * G_ + g]); continue; }
    j -= NWI;
    if (j < NWO) { size_t o = j >> 9, k = j & 511; WoT[j] = f2b(Wo[k * O_ + o]); continue; }
    j -= NWO;
    if (j < NH8) {
      uint4v sv = {0x7FC07FC0u, 0x7FC07FC0u, 0x7FC07FC0u, 0x7FC07FC0u};
      ((uint4v*)hs)[j] = sv;
      continue;
    }
    j -= NH8;
    xccbuf[j] = 0u;
  }
}

// ---------------------------------------------------------------- scan ------
// 128 WGs launched; active iff (wg&7)<4. group = wg&7 (16 rows), slice = wg>>3
// (32 h-cols). Under round-robin dispatch a group's 16 WGs share one XCD.
// wave = s*3 + gk; wave's gate-cols = gk*512 + slice*32 + s*16.
__global__ __launch_bounds__(384, 2) void scan_kernel(
    const unsigned short* __restrict__ xb,
    const unsigned short* __restrict__ WhT,
    const unsigned short* __restrict__ WiT,
    unsigned short* __restrict__ hs,
    const float* __restrict__ bi,
    const float* __restrict__ bhn,
    const float* __restrict__ h0,
    unsigned* __restrict__ xccbuf)
{
  const int wg = blockIdx.x;
  const int group = wg & 7;
  if (group >= 4) return;                     // 64 active WGs on XCDs 0..3
  const int slice = wg >> 3;
  const int tid = threadIdx.x;
  const int wave = tid >> 6;
  const int lane = tid & 63;
  const int m = lane & 15;
  const int quad = lane >> 4;
  const int gk = wave % 3;
  const int s = wave / 3;
  const int row0 = group * 16;
  const int jbase = slice * 32 + s * 16;
  const int gcol = gk * 512 + jbase + m;

  __shared__ unsigned short hT[16 * 512];     // h tile, XOR-swizzled 16B blocks
  struct HX { float h, x; };
  __shared__ HX lds_hx[6][256];               // pre-activation exchange
  __shared__ unsigned short h_out[16 * 32];   // this WG's h slice (repack)
  __shared__ int fast_lds;

  // persistent B fragments (weights live in registers for the whole scan)
  short8 Bh[16], Bx[8];
  {
    const unsigned short* p = WhT + (size_t)gcol * H_ + quad * 8;
#pragma unroll
    for (int k = 0; k < 16; ++k) Bh[k] = *(const short8*)(p + k * 32);
    const unsigned short* q = WiT + (size_t)gcol * D_ + quad * 8;
#pragma unroll
    for (int k = 0; k < 8; ++k) Bx[k] = *(const short8*)(q + k * 32);
  }

  const int jcol = jbase + m;
  const float bi_r = bi[jcol];
  const float bi_z = bi[512 + jcol];
  const float bi_n = bi[1024 + jcol];
  const float bhn_c = bhn[jcol];
  float hold[4];
#pragma unroll
  for (int i = 0; i < 4; ++i)
    hold[i] = h0[(size_t)(row0 + quad * 4 + i) * H_ + jcol];

  // preamble: h0 -> hT (bf16, swizzled)
  for (int i = tid; i < 16 * 512; i += 384) {
    int r = i >> 9, c = i & 511;
    int c2 = (((c >> 3) ^ (r & 7)) << 3) | (c & 7);
    hT[r * 512 + c2] = f2b(h0[(size_t)(row0 + r) * H_ + c]);
  }
  // accx for t=0
  float4v accx = {0.f, 0.f, 0.f, 0.f};
  {
    const unsigned short* xp = xb + ((size_t)0 * B_ + row0 + m) * D_ + quad * 8;
#pragma unroll
    for (int k = 0; k < 8; ++k)
      accx = __builtin_amdgcn_mfma_f32_16x16x32_bf16(*(const short8*)(xp + k * 32), Bx[k], accx, 0, 0, 0);
  }

  // ---- one-time XCD-homogeneity consensus (per group; identical verdicts) --
  {
    unsigned xcc;
    asm("s_getreg_b32 %0, hwreg(HW_REG_XCC_ID)" : "=s"(xcc));
    if (tid == 0) {
      unsigned tok = xcc + 1u;
      unsigned* slot = xccbuf + wg;
      asm volatile("global_store_dword %0, %1, off sc0 sc1"
                   :: "v"(slot), "v"(tok) : "memory");
    }
    if (wave == 0) {
      unsigned v = 0xffffffffu;
      if (lane < 16) {
        const unsigned* p = xccbuf + group + 8 * lane;   // the 16 group members
        do {
          asm volatile("global_load_dword %0, %1, off sc0 sc1\n\t"
                       "s_waitcnt vmcnt(0)" : "=&v"(v) : "v"(p));
        } while (v == 0u);
      }
      unsigned ref = __shfl(v, 0, 64);
      bool ok = (lane < 16) ? (v == ref) : true;
      if (lane == 0) fast_lds = (__ballot(ok) == ~0ull) ? 1 : 0;
    }
  }
  __syncthreads();
  const bool fast = (fast_lds != 0);

  for (int t = 0; t < T_; ++t) {
    // h-part MFMAs from LDS tile (two accumulators -> half dep-chain depth)
    float4v acch0 = {0.f, 0.f, 0.f, 0.f}, acch1 = {0.f, 0.f, 0.f, 0.f};
#pragma unroll
    for (int k = 0; k < 16; k += 2) {
      const int blk0 = (k * 4 + quad) ^ (m & 7);
      short8 a0 = *(const short8*)&hT[m * 512 + blk0 * 8];
      acch0 = __builtin_amdgcn_mfma_f32_16x16x32_bf16(a0, Bh[k], acch0, 0, 0, 0);
      const int blk1 = ((k + 1) * 4 + quad) ^ (m & 7);
      short8 a1 = *(const short8*)&hT[m * 512 + blk1 * 8];
      acch1 = __builtin_amdgcn_mfma_f32_16x16x32_bf16(a1, Bh[k + 1], acch1, 0, 0, 0);
    }
    // exchange pre-activations (h-part + x-part packed as one b64 each)
#pragma unroll
    for (int i = 0; i < 4; ++i) {
      const int idx = (quad * 4 + i) * 16 + m;
      HX v; v.h = acch0[i] + acch1[i]; v.x = accx[i];
      lds_hx[wave][idx] = v;
    }
    __syncthreads();
    if (gk == 0) {
      const int wb = s * 3;
#pragma unroll
      for (int i = 0; i < 4; ++i) {
        const int r = quad * 4 + i;
        const int idx = r * 16 + m;
        const HX vr = lds_hx[wb + 0][idx];
        const HX vz = lds_hx[wb + 1][idx];
        const HX vn = lds_hx[wb + 2][idx];
        const float pr = vr.h + vr.x + bi_r;
        const float pz = vz.h + vz.x + bi_z;
        const float rg = 1.f / (1.f + __expf(-pr));
        const float zg = 1.f / (1.f + __expf(-pz));
        const float an = vn.x + bi_n + rg * (vn.h + bhn_c);
        const float e2 = __expf(2.f * an);          // branch-free tanh
        const float ng = 1.f - 2.f / (e2 + 1.f);
        const float hn = (1.f - zg) * ng + zg * hold[i];
        hold[i] = hn;
        h_out[r * 32 + s * 16 + m] = f2b(hn);
      }
    }
    // issue x loads for t+1 early (overlap store visibility + poll)
    short8 xa[8];
    if (t < T_ - 1) {
      const unsigned short* xp = xb + ((size_t)(t + 1) * B_ + row0 + m) * D_ + quad * 8;
#pragma unroll
      for (int k = 0; k < 8; ++k) xa[k] = *(const short8*)(xp + k * 32);
    }
    __syncthreads();
    // one wave stores this WG's 1KB h slice as 64x16B stores.
    // fast: sc0 write-back into the group's shared XCD L2 (~200cyc visible);
    // slow: sc0sc1 write-through to MALL (device scope).
    if (wave == 1) {
      const int r = lane >> 2, c8 = (lane & 3) * 8;
      short8 hv = *(const short8*)&h_out[r * 32 + c8];
      unsigned short* dst = hs + ((size_t)t * B_ + row0 + r) * H_ + slice * 32 + c8;
      if (fast)
        asm volatile("global_store_dwordx4 %0, %1, off sc0"
                     :: "v"(dst), "v"(hv) : "memory");
      else
        asm volatile("global_store_dwordx4 %0, %1, off sc0 sc1"
                     :: "v"(dst), "v"(hv) : "memory");
    }
    if (t < T_ - 1) {
      // poll hs[t] tile (16 rows x 512 = 1024 x 16B chunks); a chunk is ready
      // when none of its 8 bf16 equal the sentinel. fast: sc0 loads (L1 bypass,
      // served by the shared L2). slow: sc0sc1 (read-through from MALL).
      const unsigned short* src = hs + ((size_t)t * B_ + row0) * H_;
      const int c0 = tid, c1 = tid + 384;
      const int c2r = tid + 768;
      const int c2 = (c2r < 1024) ? c2r : c0;     // dup for tail threads
      const short8* p0 = (const short8*)(src + (size_t)c0 * 8);
      const short8* p1 = (const short8*)(src + (size_t)c1 * 8);
      const short8* p2 = (const short8*)(src + (size_t)c2 * 8);
      short8 v0, v1, v2;
      bool bad;
      if (fast) {
        do {
          asm volatile(
              "global_load_dwordx4 %0, %3, off sc0\n\t"
              "global_load_dwordx4 %1, %4, off sc0\n\t"
              "global_load_dwordx4 %2, %5, off sc0\n\t"
              "s_waitcnt vmcnt(0)"
              : "=&v"(v0), "=&v"(v1), "=&v"(v2)
              : "v"(p0), "v"(p1), "v"(p2));
          bad = false;
#pragma unroll
          for (int e = 0; e < 8; ++e) {
            bad |= ((unsigned short)v0[e] == (unsigned short)SENT);
            bad |= ((unsigned short)v1[e] == (unsigned short)SENT);
            bad |= ((unsigned short)v2[e] == (unsigned short)SENT);
          }
        } while (bad);
      } else {
        do {
          asm volatile(
              "global_load_dwordx4 %0, %3, off sc0 sc1\n\t"
              "global_load_dwordx4 %1, %4, off sc0 sc1\n\t"
              "global_load_dwordx4 %2, %5, off sc0 sc1\n\t"
              "s_waitcnt vmcnt(0)"
              : "=&v"(v0), "=&v"(v1), "=&v"(v2)
              : "v"(p0), "v"(p1), "v"(p2));
          bad = false;
#pragma unroll
          for (int e = 0; e < 8; ++e) {
            bad |= ((unsigned short)v0[e] == (unsigned short)SENT);
            bad |= ((unsigned short)v1[e] == (unsigned short)SENT);
            bad |= ((unsigned short)v2[e] == (unsigned short)SENT);
          }
        } while (bad);
      }
      // write hT swizzled
      { const int r = c0 >> 6, b2 = (c0 & 63) ^ (r & 7); *(short8*)&hT[r * 512 + b2 * 8] = v0; }
      { const int r = c1 >> 6, b2 = (c1 & 63) ^ (r & 7); *(short8*)&hT[r * 512 + b2 * 8] = v1; }
      if (c2r < 1024) { const int r = c2r >> 6, b2 = (c2r & 63) ^ (r & 7); *(short8*)&hT[r * 512 + b2 * 8] = v2; }
      // x MFMAs for t+1 (two accumulators)
      float4v ax0 = {0.f, 0.f, 0.f, 0.f}, ax1 = {0.f, 0.f, 0.f, 0.f};
#pragma unroll
      for (int k = 0; k < 8; k += 2) {
        ax0 = __builtin_amdgcn_mfma_f32_16x16x32_bf16(xa[k], Bx[k], ax0, 0, 0, 0);
        ax1 = __builtin_amdgcn_mfma_f32_16x16x32_bf16(xa[k + 1], Bx[k + 1], ax1, 0, 0, 0);
      }
#pragma unroll
      for (int i = 0; i < 4; ++i) accx[i] = ax0[i] + ax1[i];
      __syncthreads();
    }
  }
}

// ---------------------------------------------------------------- ogemm -----
__global__ __launch_bounds__(256) void ogemm_kernel(
    const unsigned short* __restrict__ hs, const unsigned short* __restrict__ WoT,
    const float* __restrict__ bo, float* __restrict__ out)
{
  const int wv = threadIdx.x >> 6, lane = threadIdx.x & 63;
  const int m = lane & 15, quad = lane >> 4;
  const int rowbase = blockIdx.x * 64 + wv * 16;
  const unsigned short* ap = hs + (size_t)(rowbase + m) * H_ + quad * 8;
  float4v acc[16];
#pragma unroll
  for (int n = 0; n < 16; ++n) { float4v z = {0.f,0.f,0.f,0.f}; acc[n] = z; }
#pragma unroll
  for (int k = 0; k < 16; ++k) {
    short8 a = *(const short8*)(ap + k * 32);
#pragma unroll
    for (int n = 0; n < 16; ++n) {
      short8 b = *(const short8*)(WoT + (size_t)(n * 16 + m) * H_ + k * 32 + quad * 8);
      acc[n] = __builtin_amdgcn_mfma_f32_16x16x32_bf16(a, b, acc[n], 0, 0, 0);
    }
  }
#pragma unroll
  for (int n = 0; n < 16; ++n) {
    const int col = n * 16 + m;
    const float bias = bo[col];
#pragma unroll
    for (int i = 0; i < 4; ++i) {
      const int r = rowbase + quad * 4 + i;
      out[(size_t)r * O_ + col] = acc[n][i] + bias;
    }
  }
}

// ---------------------------------------------------------------- launch ----
extern "C" void kernel_launch(void* const* d_in, const int* in_sizes, int n_in,
                              void* d_out, int out_size, void* d_ws, size_t ws_size,
                              hipStream_t stream)
{
  const float* x   = (const float*)d_in[0];
  const float* Wi  = (const float*)d_in[1];
  const float* bi  = (const float*)d_in[2];
  const float* Wh  = (const float*)d_in[3];
  const float* bhn = (const float*)d_in[4];
  const float* Wo  = (const float*)d_in[5];
  const float* bo  = (const float*)d_in[6];
  const float* h0  = (const float*)d_in[7];
  float* out = (float*)d_out;

  char* ws = (char*)d_ws;
  unsigned short* xb  = (unsigned short*)ws;  ws += (size_t)T_ * B_ * D_ * 2;  // 33.5 MB
  unsigned short* WhT = (unsigned short*)ws;  ws += (size_t)G_ * H_ * 2;       // 1.5 MB
  unsigned short* WiT = (unsigned short*)ws;  ws += (size_t)G_ * D_ * 2;       // 0.75 MB
  unsigned short* WoT = (unsigned short*)ws;  ws += (size_t)O_ * H_ * 2;       // 0.25 MB
  unsigned short* hs  = (unsigned short*)ws;  ws += (size_t)T_ * B_ * H_ * 2;  // 67 MB
  unsigned* xccbuf    = (unsigned*)ws;                                          // 512 B

  prep_kernel<<<4096, 256, 0, stream>>>(x, Wi, Wh, Wo, xb, WhT, WiT, WoT, hs, xccbuf);
  scan_kernel<<<128, 384, 0, stream>>>(xb, WhT, WiT, hs, bi, bhn, h0, xccbuf);
  ogemm_kernel<<<1024, 256, 0, stream>>>(hs, WoT, bo, out);
}